// Round 1
// baseline (190.627 us; speedup 1.0000x reference)
//
#include <hip/hip_runtime.h>
#include <hip/hip_bf16.h>

// out[b,d1,d2] = (x[b,d1,d2,3] > 0.5f) ? (float)d1 : 0.0f
// x: [8, 1024, 1024, 4] fp32 contiguous. out: [8, 1024, 1024] fp32.
// Memory-bound: 134 MB read + 33.5 MB write -> ~27 us floor at 6.3 TB/s.

__global__ __launch_bounds__(256) void Model_58609123721280_kernel(
    const float4* __restrict__ x4,  // one float4 per element (c0..c3)
    float* __restrict__ out,
    int n)                          // total elements = B*D1*D2
{
    int i = blockIdx.x * blockDim.x + threadIdx.x;
    if (i >= n) return;
    float4 v = x4[i];                       // coalesced 16 B/lane
    float d1 = (float)((i >> 10) & 1023);   // D2 = 1024, D1 = 1024
    out[i] = (v.w > 0.5f) ? d1 : 0.0f;      // coalesced 4 B/lane
}

extern "C" void kernel_launch(void* const* d_in, const int* in_sizes, int n_in,
                              void* d_out, int out_size, void* d_ws, size_t ws_size,
                              hipStream_t stream) {
    const float4* x4 = (const float4*)d_in[0];
    float* out = (float*)d_out;
    int n = out_size;                        // 8*1024*1024 = 8388608
    int block = 256;
    int grid = (n + block - 1) / block;      // 32768 blocks
    Model_58609123721280_kernel<<<grid, block, 0, stream>>>(x4, out, n);
}